// Round 7
// baseline (503.987 us; speedup 1.0000x reference)
//
#include <hip/hip_runtime.h>
#include <stdint.h>
#include <math.h>

typedef _Float16 f16;
typedef _Float16 f16x8 __attribute__((ext_vector_type(8)));
typedef float f32x16 __attribute__((ext_vector_type(16)));

#define KD 704
#define NPTS 8192

typedef const unsigned __attribute__((address_space(1)))* gas_ptr;
typedef unsigned __attribute__((address_space(3)))* las_ptr;

__device__ __forceinline__ void gld16(const void* g, void* l) {
  __builtin_amdgcn_global_load_lds((gas_ptr)g, (las_ptr)l, 16, 0, 0);
}

__device__ __forceinline__ unsigned long long packkey(float v, int idx) {
  unsigned b = __float_as_uint(v);
  b ^= ((unsigned)((int)b >> 31)) | 0x80000000u;  // monotone float->uint
  return ((unsigned long long)b << 32) | (unsigned)(~idx);  // ~idx: ties -> smaller idx
}

// ---- kernel 1: column norms (x256 fold) + zero the 16K atomic slots ----
__global__ void k_norm(const float* __restrict__ A, const float* __restrict__ B,
                       float* __restrict__ invA, float* __restrict__ invB,
                       unsigned long long* __restrict__ slots) {
  __shared__ float p[256];
  const int blk = blockIdx.x;  // 0..511
  const int mat = blk >> 8;
  const float* M = mat ? B : A;
  float* inv = mat ? invB : invA;
  const int cbase = (blk & 255) << 5;
  const int c = cbase + (threadIdx.x & 31);
  const int s = threadIdx.x >> 5;  // 0..7
  float ss = 0.f;
  for (int d = s; d < KD; d += 8) {
    float x = M[(size_t)d * NPTS + c];
    ss = fmaf(x, x, ss);
  }
  p[threadIdx.x] = ss;
  if (blk < 64) slots[blk * 256 + threadIdx.x] = 0ull;  // rowbest+colbest (128 KB)
  __syncthreads();
  if (threadIdx.x < 32) {
    float t = 0.f;
    #pragma unroll
    for (int k = 0; k < 8; ++k) t += p[k * 32 + threadIdx.x];
    inv[cbase + threadIdx.x] = 256.0f / sqrtf(t);
  }
}

// ---- kernel 2: transpose (D,N)->(N,D), normalize, fp16 hi/lo split ----
__global__ void k_split(const float* __restrict__ A, const float* __restrict__ B,
                        const float* __restrict__ invA, const float* __restrict__ invB,
                        f16* __restrict__ Ahi, f16* __restrict__ Alo,
                        f16* __restrict__ Bhi, f16* __restrict__ Blo) {
  __shared__ float t[32][33];
  const int z = blockIdx.z;
  const float* M   = z ? B    : A;
  const float* inv = z ? invB : invA;
  f16* Hi = z ? Bhi : Ahi;
  f16* Lo = z ? Blo : Alo;
  const int c0 = blockIdx.x * 32, d0 = blockIdx.y * 32;
  const int tx = threadIdx.x & 31, ty = threadIdx.x >> 5;
  #pragma unroll
  for (int s = 0; s < 4; ++s)
    t[ty + s * 8][tx] = M[(size_t)(d0 + ty + s * 8) * NPTS + (c0 + tx)];
  __syncthreads();
  const int tx16 = threadIdx.x & 15, ty16 = threadIdx.x >> 4;  // 16x16
  #pragma unroll
  for (int s2 = 0; s2 < 2; ++s2) {
    const int i = c0 + ty16 + s2 * 16;
    const float iv = inv[i];
    const float v0 = t[tx16 * 2][ty16 + s2 * 16] * iv;
    const float v1 = t[tx16 * 2 + 1][ty16 + s2 * 16] * iv;
    const f16 h0 = (f16)v0, h1 = (f16)v1;
    const f16 l0 = (f16)(v0 - (float)h0), l1 = (f16)(v1 - (float)h1);
    const size_t o = (size_t)i * KD + d0 + tx16 * 2;
    Hi[o] = h0; Hi[o + 1] = h1;
    Lo[o] = l0; Lo[o + 1] = l1;
  }
}

// ---- kernel 3: 128x128-tile GEMM, 32x32x16 MFMA (f16 hi/lo, 3 products) + top-1 ----
// Staging + swizzle identical to the verified round-3/5 kernel; only the
// fragment shape and the C/D-layout-dependent reductions change.
__global__ __launch_bounds__(256, 2)
void k_gemm_top1(const f16* __restrict__ Ahi, const f16* __restrict__ Alo,
                 const f16* __restrict__ Bhi, const f16* __restrict__ Blo,
                 unsigned long long* rowbest, unsigned long long* colbest) {
  __shared__ f16 sAh[128 * 64];
  __shared__ f16 sAl[128 * 64];
  __shared__ f16 sBh[128 * 64];
  __shared__ f16 sBl[128 * 64];

  const int tid = threadIdx.x, lane = tid & 63, wave = tid >> 6;
  const int bj = blockIdx.x & 63, bi = blockIdx.x >> 6;
  const int wr = wave >> 1, wc = wave & 1;

  f32x16 acc[2][2] = {};  // 2x2 fragments of 32x32; per-wave 64x64 output

  // staging (verbatim from round 3/5): wave w stages rows [w*32, w*32+32).
  const int srow = wave * 32 + (lane >> 3);
  const int cs   = ((lane & 7) ^ (srow & 7)) * 16;
  const size_t rowbytes = (size_t)KD * 2;  // 1408
  const char* pAh = (const char*)Ahi + (size_t)(bi * 128 + srow) * rowbytes + cs;
  const char* pAl = (const char*)Alo + (size_t)(bi * 128 + srow) * rowbytes + cs;
  const char* pBh = (const char*)Bhi + (size_t)(bj * 128 + srow) * rowbytes + cs;
  const char* pBl = (const char*)Blo + (size_t)(bj * 128 + srow) * rowbytes + cs;
  const unsigned lbase = wave * 4096;

  const int l31 = lane & 31, l7 = lane & 7, h16 = lane >> 5;  // h16: k-half select

  for (int ks = 0; ks < 11; ++ks) {
    const size_t kb = (size_t)ks * 128;
    #pragma unroll
    for (int q = 0; q < 4; ++q) {
      size_t go = kb + (size_t)q * 8 * rowbytes;
      unsigned lo_ = lbase + q * 1024;
      gld16(pAh + go, (char*)sAh + lo_);
      gld16(pAl + go, (char*)sAl + lo_);
      gld16(pBh + go, (char*)sBh + lo_);
      gld16(pBl + go, (char*)sBl + lo_);
    }
    __syncthreads();

    // 4 k-steps of 16 within the BK=64 tile.
    // A/B frag (32x32x16): row = base + (lane&31), k = s*16 + (lane>>5)*8 + j
    //  -> 16B slot g = s*2 + (lane>>5); swizzled slot g ^ (row&7), row&7 == lane&7.
    #pragma unroll
    for (int s = 0; s < 4; ++s) {
      const int sb = ((s * 2 + h16) ^ l7) << 4;
      f16x8 ah[2], al[2], bh[2], bl[2];
      #pragma unroll
      for (int ai = 0; ai < 2; ++ai) {
        const int row = wr * 64 + ai * 32 + l31;
        ah[ai] = *(const f16x8*)((const char*)sAh + row * 128 + sb);
        al[ai] = *(const f16x8*)((const char*)sAl + row * 128 + sb);
      }
      #pragma unroll
      for (int bjx = 0; bjx < 2; ++bjx) {
        const int row = wc * 64 + bjx * 32 + l31;
        bh[bjx] = *(const f16x8*)((const char*)sBh + row * 128 + sb);
        bl[bjx] = *(const f16x8*)((const char*)sBl + row * 128 + sb);
      }
      // 3 products; same-acc ops spaced 4 apart for latency cover
      #pragma unroll
      for (int ai = 0; ai < 2; ++ai)
        #pragma unroll
        for (int bjx = 0; bjx < 2; ++bjx)
          acc[ai][bjx] = __builtin_amdgcn_mfma_f32_32x32x16_f16(ah[ai], bh[bjx], acc[ai][bjx], 0, 0, 0);
      #pragma unroll
      for (int ai = 0; ai < 2; ++ai)
        #pragma unroll
        for (int bjx = 0; bjx < 2; ++bjx)
          acc[ai][bjx] = __builtin_amdgcn_mfma_f32_32x32x16_f16(ah[ai], bl[bjx], acc[ai][bjx], 0, 0, 0);
      #pragma unroll
      for (int ai = 0; ai < 2; ++ai)
        #pragma unroll
        for (int bjx = 0; bjx < 2; ++bjx)
          acc[ai][bjx] = __builtin_amdgcn_mfma_f32_32x32x16_f16(al[ai], bh[bjx], acc[ai][bjx], 0, 0, 0);
    }
    __syncthreads();
  }

  // ---- fused top-1. 32x32 C/D: col = lane&31, row = (r&3) + 8*(r>>2) + 4*(lane>>5) ----
  const float scale = 1.0f / 65536.0f;  // undo 256^2
  const int R0 = bi * 128 + wr * 64;
  const int C0 = bj * 128 + wc * 64;

  // rows: per (ai, r), the 32-lane half (lane>>5) owns one output row;
  // its 64 cols live across (bj-frag, lane&31).
  #pragma unroll
  for (int ai = 0; ai < 2; ++ai) {
    #pragma unroll
    for (int r = 0; r < 16; ++r) {
      float bv = acc[ai][0][r];
      int bjx = C0 + l31;
      float v = acc[ai][1][r];
      if (v > bv) { bv = v; bjx = C0 + 32 + l31; }
      unsigned long long key = packkey(bv * scale, bjx);
      #pragma unroll
      for (int off = 1; off < 32; off <<= 1) {  // reduce within each 32-lane half
        unsigned long long o = __shfl_xor(key, off);
        if (o > key) key = o;
      }
      if (l31 == 0) {
        const int row = R0 + ai * 32 + (r & 3) + 8 * (r >> 2) + 4 * h16;
        atomicMax(&rowbest[row], key);
      }
    }
  }
  // cols: per bj-frag, lane&31 owns one column; rows spread over (ai, r, lane>>5).
  #pragma unroll
  for (int bjx = 0; bjx < 2; ++bjx) {
    unsigned long long key = 0ull;
    #pragma unroll
    for (int ai = 0; ai < 2; ++ai)
      #pragma unroll
      for (int r = 0; r < 16; ++r) {
        const int row = R0 + ai * 32 + (r & 3) + 8 * (r >> 2) + 4 * h16;
        unsigned long long k2 = packkey(acc[ai][bjx][r] * scale, row);
        if (k2 > key) key = k2;
      }
    unsigned long long o = __shfl_xor(key, 32);  // merge the two halves
    if (o > key) key = o;
    if (lane < 32) atomicMax(&colbest[C0 + bjx * 32 + lane], key);
  }
}

// ---- kernel 4: mutual-NN mask + output assembly (all f32) ----
__global__ void k_epilogue(const unsigned long long* __restrict__ rowbest,
                           const unsigned long long* __restrict__ colbest,
                           float* __restrict__ out) {
  int i = blockIdx.x * 256 + threadIdx.x;  // 0..8191
  unsigned long long rk = rowbest[i];
  int j = (int)(~(unsigned)rk);
  unsigned hb = (unsigned)(rk >> 32);
  hb ^= (hb >> 31) ? 0x80000000u : 0xFFFFFFFFu;
  float sim = __uint_as_float(hb);
  unsigned long long ck = colbest[j];
  int nn21 = (int)(~(unsigned)ck);
  bool m = (nn21 == i);
  out[2 * i]     = m ? (float)i : -1.0f;
  out[2 * i + 1] = m ? (float)j : -1.0f;
  out[2 * NPTS + i] = m ? sim : 0.0f;
  out[3 * NPTS + i] = m ? 1.0f : 0.0f;
}

extern "C" void kernel_launch(void* const* d_in, const int* in_sizes, int n_in,
                              void* d_out, int out_size, void* d_ws, size_t ws_size,
                              hipStream_t stream) {
  const float* A = (const float*)d_in[0];
  const float* B = (const float*)d_in[1];
  char* ws = (char*)d_ws;

  const size_t SPLIT = (size_t)NPTS * KD * 2;  // 11,534,336 B per array
  unsigned long long* rowbest = (unsigned long long*)(ws);
  unsigned long long* colbest = (unsigned long long*)(ws + 65536);
  float* invA = (float*)(ws + 131072);
  float* invB = (float*)(ws + 163840);
  f16* Ahi = (f16*)(ws + 196608);
  f16* Alo = (f16*)(ws + 196608 + SPLIT);
  f16* Bhi = (f16*)(ws + 196608 + 2 * SPLIT);
  f16* Blo = (f16*)(ws + 196608 + 3 * SPLIT);

  k_norm<<<512, 256, 0, stream>>>(A, B, invA, invB, rowbest /* + colbest contig */);
  dim3 g2(NPTS / 32, KD / 32, 2);
  k_split<<<g2, 256, 0, stream>>>(A, B, invA, invB, Ahi, Alo, Bhi, Blo);
  k_gemm_top1<<<4096, 256, 0, stream>>>(Ahi, Alo, Bhi, Blo, rowbest, colbest);
  k_epilogue<<<NPTS / 256, 256, 0, stream>>>(rowbest, colbest, (float*)d_out);
}

// Round 8
// 399.168 us; speedup vs baseline: 1.2626x; 1.2626x over previous
//
#include <hip/hip_runtime.h>
#include <stdint.h>
#include <math.h>

typedef _Float16 f16;
typedef _Float16 f16x8 __attribute__((ext_vector_type(8)));
typedef float f32x4 __attribute__((ext_vector_type(4)));

#define KD 704
#define NPTS 8192

typedef const unsigned __attribute__((address_space(1)))* gas_ptr;
typedef unsigned __attribute__((address_space(3)))* las_ptr;

__device__ __forceinline__ void gld16(const void* g, void* l) {
  __builtin_amdgcn_global_load_lds((gas_ptr)g, (las_ptr)l, 16, 0, 0);
}

__device__ __forceinline__ unsigned long long packkey(float v, int idx) {
  unsigned b = __float_as_uint(v);
  b ^= ((unsigned)((int)b >> 31)) | 0x80000000u;  // monotone float->uint
  return ((unsigned long long)b << 32) | (unsigned)(~idx);  // ~idx: ties -> smaller idx
}

// ---- kernel 1 (fused): column norms + normalize + fp16 hi/lo split + slot init ----
// One block owns a full 704x32 column-block in LDS; one input pass instead of two.
__global__ __launch_bounds__(256)
void k_normsplit(const float* __restrict__ A, const float* __restrict__ B,
                 f16* __restrict__ Ahi, f16* __restrict__ Alo,
                 f16* __restrict__ Bhi, f16* __restrict__ Blo,
                 unsigned long long* __restrict__ slots) {
  __shared__ float t[KD][33];   // +1 pad: bank = (d + c) & 31
  __shared__ float p[256];
  __shared__ float invs[32];
  const int tid = threadIdx.x;
  const int blk = blockIdx.x;   // 0..511
  const int mat = blk >> 8;
  const float* M = mat ? B : A;
  f16* Hi = mat ? Bhi : Ahi;
  f16* Lo = mat ? Blo : Alo;
  const int c0 = (blk & 255) << 5;

  if (blk < 64) slots[blk * 256 + tid] = 0ull;  // rowbest+colbest (128 KB contig)

  // load tile (coalesced 128B rows)
  const int lc = tid & 31;
  const int ld0 = tid >> 5;  // 0..7
  for (int d = ld0; d < KD; d += 8)
    t[d][lc] = M[(size_t)d * NPTS + c0 + lc];
  __syncthreads();

  // per-column sumsq, 8 partials/column (same order as the verified k_norm)
  float ss = 0.f;
  for (int d = ld0; d < KD; d += 8) {
    float x = t[d][lc];
    ss = fmaf(x, x, ss);
  }
  p[tid] = ss;
  __syncthreads();
  if (tid < 32) {
    float s = 0.f;
    #pragma unroll
    for (int k = 0; k < 8; ++k) s += p[k * 32 + tid];
    invs[tid] = 256.0f / sqrtf(s);  // fold split-scale S=256 into normalization
  }
  __syncthreads();

  // split + write: wave w handles columns [w*8, w*8+8); 128B contiguous stores
  const int wv = tid >> 6, ln = tid & 63;
  for (int ci = 0; ci < 8; ++ci) {
    const int c = wv * 8 + ci;
    const float iv = invs[c];
    const size_t ob = (size_t)(c0 + c) * KD;
    #pragma unroll
    for (int it = 0; it < 11; ++it) {
      const int d = it * 64 + ln;
      float v = t[d][c] * iv;
      f16 h = (f16)v;
      f16 l = (f16)(v - (float)h);
      Hi[ob + d] = h;
      Lo[ob + d] = l;
    }
  }
}

// ---- kernel 2: 128x128-tile GEMM (f16 hi/lo, 3 products) + fused top-1 atomics ----
// (round-3/5 version VERBATIM: verified 310-317 us, 0 bank conflicts, absmax <= 1 ulp)
__global__ __launch_bounds__(256, 2)
void k_gemm_top1(const f16* __restrict__ Ahi, const f16* __restrict__ Alo,
                 const f16* __restrict__ Bhi, const f16* __restrict__ Blo,
                 unsigned long long* rowbest, unsigned long long* colbest) {
  // LDS tiles: [128 rows][64 k] f16 = 128B rows; XOR-8 swizzle on 16B slots.
  __shared__ f16 sAh[128 * 64];
  __shared__ f16 sAl[128 * 64];
  __shared__ f16 sBh[128 * 64];
  __shared__ f16 sBl[128 * 64];

  const int tid = threadIdx.x, lane = tid & 63, wave = tid >> 6;
  const int bj = blockIdx.x & 63, bi = blockIdx.x >> 6;
  const int wr = wave >> 1, wc = wave & 1;

  f32x4 acc[4][4] = {};

  // staging: wave w stages rows [w*32, w*32+32) of each tile; 4 instrs/tile.
  // LDS dest is linear (base + lane*16); global source is pre-swizzled:
  // data for (row, col-slot c) lands at LDS slot c ^ (row&7).
  const int srow = wave * 32 + (lane >> 3);        // q adds 8 -> (srow+q*8)&7 == srow&7
  const int cs   = ((lane & 7) ^ (srow & 7)) * 16; // swizzled source slot, bytes
  const size_t rowbytes = (size_t)KD * 2;          // 1408
  const char* pAh = (const char*)Ahi + (size_t)(bi * 128 + srow) * rowbytes + cs;
  const char* pAl = (const char*)Alo + (size_t)(bi * 128 + srow) * rowbytes + cs;
  const char* pBh = (const char*)Bhi + (size_t)(bj * 128 + srow) * rowbytes + cs;
  const char* pBl = (const char*)Blo + (size_t)(bj * 128 + srow) * rowbytes + cs;
  const unsigned lbase = wave * 4096;  // bytes; + q*1024; HW adds lane*16

  for (int ks = 0; ks < 11; ++ks) {
    const size_t kb = (size_t)ks * 128;  // k0 * 2 bytes
    #pragma unroll
    for (int q = 0; q < 4; ++q) {
      size_t go = kb + (size_t)q * 8 * rowbytes;
      unsigned lo_ = lbase + q * 1024;
      gld16(pAh + go, (char*)sAh + lo_);
      gld16(pAl + go, (char*)sAl + lo_);
      gld16(pBh + go, (char*)sBh + lo_);
      gld16(pBl + go, (char*)sBl + lo_);
    }
    __syncthreads();  // drains vmcnt before barrier (compiler-inserted)

    #pragma unroll
    for (int kk = 0; kk < 2; ++kk) {
      f16x8 ah[4], al[4], bh[4], bl[4];
      const int sa = ((kk * 4 + (lane >> 4)) ^ (lane & 7)) * 16;  // swizzled read slot
      #pragma unroll
      for (int a = 0; a < 4; ++a) {
        int row = wr * 64 + a * 16 + (lane & 15);
        ah[a] = *(const f16x8*)((const char*)sAh + row * 128 + sa);
        al[a] = *(const f16x8*)((const char*)sAl + row * 128 + sa);
      }
      #pragma unroll
      for (int b = 0; b < 4; ++b) {
        int row = wc * 64 + b * 16 + (lane & 15);
        bh[b] = *(const f16x8*)((const char*)sBh + row * 128 + sa);
        bl[b] = *(const f16x8*)((const char*)sBl + row * 128 + sa);
      }
      #pragma unroll
      for (int a = 0; a < 4; ++a)
        #pragma unroll
        for (int b = 0; b < 4; ++b) {
          acc[a][b] = __builtin_amdgcn_mfma_f32_16x16x32_f16(ah[a], bh[b], acc[a][b], 0, 0, 0);
          acc[a][b] = __builtin_amdgcn_mfma_f32_16x16x32_f16(ah[a], bl[b], acc[a][b], 0, 0, 0);
          acc[a][b] = __builtin_amdgcn_mfma_f32_16x16x32_f16(al[a], bh[b], acc[a][b], 0, 0, 0);
        }
    }
    __syncthreads();
  }

  // ---- fused top-1 reduction. C/D layout: col = lane&15, row = (lane>>4)*4 + reg ----
  const float scale = 1.0f / 65536.0f;  // undo S^2
  const int R0 = bi * 128 + wr * 64;
  const int C0 = bj * 128 + wc * 64;

  // rows: each 16-lane group (lane>>4) holds 4 rows (reg) x 4 (a); cols across lane&15 and b
  #pragma unroll
  for (int a = 0; a < 4; ++a) {
    #pragma unroll
    for (int r = 0; r < 4; ++r) {
      float bv = acc[a][0][r];
      int bjx = C0 + (lane & 15);
      #pragma unroll
      for (int b = 1; b < 4; ++b) {
        float v = acc[a][b][r];
        if (v > bv) { bv = v; bjx = C0 + b * 16 + (lane & 15); }
      }
      unsigned long long key = packkey(bv * scale, bjx);
      #pragma unroll
      for (int off = 1; off < 16; off <<= 1) {
        unsigned long long o = __shfl_xor(key, off);
        if (o > key) key = o;
      }
      if ((lane & 15) == 0) {
        int row = R0 + a * 16 + (lane >> 4) * 4 + r;
        atomicMax(&rowbest[row], key);
      }
    }
  }
  // cols: col = C0 + b*16 + (lane&15); rows spread over (lane>>4) groups and regs
  #pragma unroll
  for (int b = 0; b < 4; ++b) {
    unsigned long long key = 0ull;
    #pragma unroll
    for (int a = 0; a < 4; ++a)
      #pragma unroll
      for (int r = 0; r < 4; ++r) {
        int i = R0 + a * 16 + (lane >> 4) * 4 + r;
        unsigned long long k2 = packkey(acc[a][b][r] * scale, i);
        if (k2 > key) key = k2;
      }
    unsigned long long o = __shfl_xor(key, 16); if (o > key) key = o;
    o = __shfl_xor(key, 32); if (o > key) key = o;
    if (lane < 16) atomicMax(&colbest[C0 + b * 16 + lane], key);
  }
}

// ---- kernel 3: mutual-NN mask + output assembly (all f32) ----
__global__ void k_epilogue(const unsigned long long* __restrict__ rowbest,
                           const unsigned long long* __restrict__ colbest,
                           float* __restrict__ out) {
  int i = blockIdx.x * 256 + threadIdx.x;  // 0..8191
  unsigned long long rk = rowbest[i];
  int j = (int)(~(unsigned)rk);
  unsigned hb = (unsigned)(rk >> 32);
  hb ^= (hb >> 31) ? 0x80000000u : 0xFFFFFFFFu;
  float sim = __uint_as_float(hb);
  unsigned long long ck = colbest[j];
  int nn21 = (int)(~(unsigned)ck);
  bool m = (nn21 == i);
  out[2 * i]     = m ? (float)i : -1.0f;
  out[2 * i + 1] = m ? (float)j : -1.0f;
  out[2 * NPTS + i] = m ? sim : 0.0f;
  out[3 * NPTS + i] = m ? 1.0f : 0.0f;
}

extern "C" void kernel_launch(void* const* d_in, const int* in_sizes, int n_in,
                              void* d_out, int out_size, void* d_ws, size_t ws_size,
                              hipStream_t stream) {
  const float* A = (const float*)d_in[0];
  const float* B = (const float*)d_in[1];
  char* ws = (char*)d_ws;

  const size_t SPLIT = (size_t)NPTS * KD * 2;  // 11,534,336 B per array
  unsigned long long* rowbest = (unsigned long long*)(ws);
  unsigned long long* colbest = (unsigned long long*)(ws + 65536);
  f16* Ahi = (f16*)(ws + 196608);
  f16* Alo = (f16*)(ws + 196608 + SPLIT);
  f16* Bhi = (f16*)(ws + 196608 + 2 * SPLIT);
  f16* Blo = (f16*)(ws + 196608 + 3 * SPLIT);

  k_normsplit<<<512, 256, 0, stream>>>(A, B, Ahi, Alo, Bhi, Blo, rowbest);
  k_gemm_top1<<<4096, 256, 0, stream>>>(Ahi, Alo, Bhi, Blo, rowbest, colbest);
  k_epilogue<<<NPTS / 256, 256, 0, stream>>>(rowbest, colbest, (float*)d_out);
}